// Round 12
// baseline (132.212 us; speedup 1.0000x reference)
//
#include <hip/hip_runtime.h>

#define N_ROWS 8192
#define NX     4096
#define DIM    512
#define BT     128          // block tile (rows & cols)
#define NT     64           // N_ROWS / BT tiles per side
#define NTRI   2080         // NT*(NT+1)/2 upper-triangle tiles
#define BK     32           // K elements per stage (64 B per row)
#define NPERS  768          // persistent blocks: exactly 3 per CU

typedef __bf16 bf16_t;
typedef bf16_t bf16x8 __attribute__((ext_vector_type(8)));
typedef float  f32x4  __attribute__((ext_vector_type(4)));

#if __has_builtin(__builtin_amdgcn_exp2f)
  #define EXP2F __builtin_amdgcn_exp2f
#else
  #define EXP2F exp2f
#endif

// ws layout (bytes):
//   0       sqrow[8192]  float   (32768 B)   exact fp32 row norms
//   32768   colsum[512]  float   ( 2048 B)
//   34816   cvals[5]     float   (   20 B)   cvals[k] = -log2e/(bw*mult_k)
//   34840   tk1          uint    (    4 B)   colsum ticket
//   34844   tk2          uint    (    4 B)   pair ticket
//   34848   S1acc        double  (    8 B)   sum of sqrow
//   34944   acc[8*16]    double  ( 1024 B)   8 accumulation slots, 128 B apart
//   36864   Zh[8192*512] bf16    (8388608 B) bf16 copy of concat(X,Y)
//
// NO __threadfence anywhere (R7/R8 A/B: per-block L2 writeback doubled
// k_pair's stage-load latency chip-wide; 108 -> 65 us when removed).
// Ordering: returning atomic -> asm sink -> s_waitcnt vmcnt(0) -> ticket.

__device__ __forceinline__ const float* zrow(const float* X, const float* Y, int r) {
    return (r < NX) ? (X + (size_t)r * DIM) : (Y + (size_t)(r - NX) * DIM);
}

// async 16B global -> LDS (lane-contiguous dest: ldsbase + lane*16)
__device__ __forceinline__ void gload_lds16(const bf16_t* g, bf16_t* l) {
    __builtin_amdgcn_global_load_lds(
        (__attribute__((address_space(1))) void*)(void*)(g),
        (__attribute__((address_space(3))) void*)(void*)(l), 16, 0, 0);
}

// fused: bf16 copy + exact fp32 row norms + zero-init of colsum/tickets.
__global__ void k_prep(const float* __restrict__ X, const float* __restrict__ Y,
                       bf16_t* __restrict__ Zh, float* __restrict__ sqrow,
                       float* __restrict__ colsum, unsigned* __restrict__ tk1,
                       double* __restrict__ S1acc) {
    int t = threadIdx.x;
    if (blockIdx.x == 0) {
        colsum[t] = 0.f; colsum[t + 256] = 0.f;
        if (t == 0) { *tk1 = 0u; *S1acc = 0.0; }
    }
    int wv = t >> 6, lane = t & 63;
    int row = blockIdx.x * 4 + wv;
    const float4* z4 = (const float4*)zrow(X, Y, row);
    float4 a = z4[lane * 2], b = z4[lane * 2 + 1];
    bf16x8 h;
    h[0] = (bf16_t)a.x; h[1] = (bf16_t)a.y; h[2] = (bf16_t)a.z; h[3] = (bf16_t)a.w;
    h[4] = (bf16_t)b.x; h[5] = (bf16_t)b.y; h[6] = (bf16_t)b.z; h[7] = (bf16_t)b.w;
    *(bf16x8*)(Zh + (size_t)row * DIM + lane * 8) = h;
    float s = a.x*a.x + a.y*a.y + a.z*a.z + a.w*a.w
            + b.x*b.x + b.y*b.y + b.z*b.z + b.w*b.w;
    #pragma unroll
    for (int off = 32; off > 0; off >>= 1) s += __shfl_down(s, off);
    if (lane == 0) sqrow[row] = s;
}

// colsum + S1 + bw, fused. 128 blocks = 16 col-groups x 8 row-slabs.
// Fence-free ticket ordering (returning atomics + vmcnt(0)).
__global__ __launch_bounds__(512) void k_colsum(const bf16_t* __restrict__ Zh,
                                                const float* __restrict__ sqrow,
                                                float* __restrict__ colsum,
                                                float* __restrict__ cvals,
                                                double* __restrict__ S1acc,
                                                unsigned* __restrict__ tk1,
                                                double* __restrict__ acc,
                                                unsigned* __restrict__ tk2) {
    __shared__ float red[8][4][8];
    __shared__ double dred[512];
    __shared__ int is_last;
    int t = threadIdx.x, lane = t & 63, wv = t >> 6;
    int n16 = lane & 15, q16 = lane >> 4;
    int g = blockIdx.x & 15, slab = blockIdx.x >> 4;
    int c0 = g * 32 + q16 * 8;
    float s[8] = {0.f, 0.f, 0.f, 0.f, 0.f, 0.f, 0.f, 0.f};
    #pragma unroll
    for (int it = 0; it < 8; ++it) {
        int r = slab * 1024 + it * 128 + wv * 16 + n16;
        bf16x8 v = *(const bf16x8*)(Zh + (size_t)r * DIM + c0);
        #pragma unroll
        for (int j = 0; j < 8; ++j) s[j] += (float)v[j];
    }
    #pragma unroll
    for (int off = 8; off >= 1; off >>= 1)
        #pragma unroll
        for (int j = 0; j < 8; ++j) s[j] += __shfl_down(s[j], off);
    if (n16 == 0)
        #pragma unroll
        for (int j = 0; j < 8; ++j) red[wv][q16][j] = s[j];
    __syncthreads();
    float oldc = 0.f;
    if (t < 32) {
        int q = t >> 3, j = t & 7;
        float v = 0.f;
        #pragma unroll
        for (int w = 0; w < 8; ++w) v += red[w][q][j];
        oldc = atomicAdd(&colsum[g * 32 + q * 8 + j], v);   // returning form
    }
    double olds = 0.0;
    if (g == 0) {   // S1 partial over this slab's 1024 rows (exact fp64)
        int i = slab * 1024 + t;
        double d = (double)sqrow[i] + (double)sqrow[i + 512];
        #pragma unroll
        for (int off = 32; off > 0; off >>= 1) d += __shfl_down(d, off);
        if (lane == 0) olds = atomicAdd(S1acc, d);          // returning form
    }
    asm volatile("" :: "v"(oldc), "v"(olds));               // keep returns live
    asm volatile("s_waitcnt vmcnt(0)" ::: "memory");        // atomics completed
    __syncthreads();
    if (t == 0) is_last = (atomicAdd(tk1, 1u) == 127u);
    __syncthreads();
    if (!is_last) return;
    // last block: bw = (2n*S1 - 2*CS) / (n^2 - n)
    float cv = atomicAdd(&colsum[t], 0.f);   // atomic read (coherent)
    dred[t] = (double)cv * (double)cv;
    __syncthreads();
    for (int off = 256; off > 0; off >>= 1) {
        if (t < off) dred[t] += dred[t + off];
        __syncthreads();
    }
    if (t < 8) acc[t * 16] = 0.0;
    if (t == 0) {
        double S1 = atomicAdd(S1acc, 0.0);   // atomic read
        double n = (double)N_ROWS;
        double sumD2 = 2.0 * n * S1 - 2.0 * dred[0];
        double bw = sumD2 / (n * n - n);
        const double LOG2E = 1.4426950408889634;
        double mult = 0.25;
        for (int k = 0; k < 5; ++k) {
            cvals[k] = (float)(-LOG2E / (bw * mult));
            mult *= 2.0;
        }
        *tk2 = 0u;
    }
}

// PERSISTENT k_pair: 768 blocks (exactly 3/CU, all resident, single
// generation), each processing 2-3 tiles (b, b+768, b+1536) with the
// proven R3/R8/R10 K-loop (3 stage buffers / 48 KB, one raw s_barrier
// per step, counted vmcnt(4), T5 setprio, supertile+XCD-local tile order,
// m89/m91-verified layouts, global-side XOR swizzle). Pipeline flows
// ACROSS tiles: steps 14/15 of tile g stage tile g+1's stages 0/1 into
// the continuing buffer rotation (buffer of global step 16g+s = (g+s)%3),
// so no cold prologue per tile. The epilogue __syncthreads' implicit
// vmcnt(0) drain is harmless: the prefetched stages land during the
// ~1500-cy exp chain. vmcnt safety invariant: at each counted wait the
// needed stage's loads are always older than the 4 newest outstanding
// ops, so stray older ops (epilogue loads, returning atomics) are merely
// force-retired. One fence-free ticket per block at the very end.
__global__ __launch_bounds__(256, 3) void k_pair(const bf16_t* __restrict__ Zh,
                                                 const float* __restrict__ sqrow,
                                                 const float* __restrict__ cvals,
                                                 double* __restrict__ acc,
                                                 unsigned* __restrict__ tk2,
                                                 float* __restrict__ out) {
    int b = blockIdx.x;
    int ntile = (b < NTRI - 2 * NPERS) ? 3 : 2;   // b<544: 3 tiles, else 2
    int tis[3], tjs[3];
    #pragma unroll
    for (int g = 0; g < 3; ++g) {
        int T = b + g * NPERS;
        int ti_ = 0, tj_ = 0;
        if (T < NTRI) {
            int q = (T & 7) * (NTRI / 8) + (T >> 3);   // XCD chunk (T&7==b&7)
            int I = 0, rem = q;                         // supertile decode
            #pragma unroll
            for (int it = 0; it < 8; ++it) {
                int rowcnt = 36 + (7 - I) * 64;
                if (rem >= rowcnt && I < 7) { rem -= rowcnt; ++I; } else break;
            }
            if (rem < 36) {            // diagonal supertile: pairs a<=bb
                int a = 0;
                #pragma unroll
                for (int it = 0; it < 7; ++it) {
                    int nxt = (a + 1) * 8 - (a + 1) * a / 2;
                    if (nxt <= rem) ++a; else break;
                }
                int off = a * 8 - a * (a - 1) / 2;
                ti_ = I * 8 + a;
                tj_ = I * 8 + a + (rem - off);
            } else {
                int r2 = rem - 36;
                int J = I + 1 + (r2 >> 6);
                int w = r2 & 63;
                ti_ = I * 8 + (w >> 3);
                tj_ = J * 8 + (w & 7);
            }
        }
        tis[g] = ti_; tjs[g] = tj_;
    }

    __shared__ bf16_t As[3][4096];   // 3 x 8 KB stage buffers
    __shared__ bf16_t Bs[3][4096];   // total 48 KB -> 3 blocks/CU
    __shared__ float wsum[4];

    int t = threadIdx.x, lane = t & 63, wv = t >> 6;
    int wr = wv >> 1, wc = wv & 1;
    int n16 = lane & 15, q16 = lane >> 4;

    // staging lane geometry (tile-independent)
    int r0_, q0_, r1_, q1_;
    { int c0 = t;       r0_ = c0 >> 2; q0_ = (c0 & 3) ^ ((r0_ >> 1) & 3);
      int c1 = 256 + t; r1_ = c1 >> 2; q1_ = (c1 & 3) ^ ((r1_ >> 1) & 3); }
    int ldsoff0 = (wv * 64) * 8;            // wave-uniform; lane*16B implicit
    int ldsoff1 = (256 + wv * 64) * 8;

    // fragment LDS element offsets (row r, logical k-chunk q16 -> phys slot)
    int aoff[4], boff[4];
    #pragma unroll
    for (int aa = 0; aa < 4; ++aa) {
        int r = 16 * (wr * 4 + aa) + n16;
        aoff[aa] = (r * 4 + (q16 ^ ((r >> 1) & 3))) * 8;
    }
    #pragma unroll
    for (int bb = 0; bb < 4; ++bb) {
        int r = 16 * (wc * 4 + bb) + n16;
        boff[bb] = (r * 4 + (q16 ^ ((r >> 1) & 3))) * 8;
    }

    float c4 = cvals[4];

#define SETPTRS(TI, TJ, A0, B0, A1, B1) do {                        \
        (A0) = Zh + (size_t)((TI) * BT + r0_) * DIM + q0_ * 8;      \
        (B0) = Zh + (size_t)((TJ) * BT + r0_) * DIM + q0_ * 8;      \
        (A1) = Zh + (size_t)((TI) * BT + r1_) * DIM + q1_ * 8;      \
        (B1) = Zh + (size_t)((TJ) * BT + r1_) * DIM + q1_ * 8;      \
    } while (0)

#define STAGEP(A0, B0, A1, B1, KN, BUF) do {                        \
        gload_lds16((A0) + (KN), &As[BUF][ldsoff0]);                \
        gload_lds16((B0) + (KN), &Bs[BUF][ldsoff0]);                \
        gload_lds16((A1) + (KN), &As[BUF][ldsoff1]);                \
        gload_lds16((B1) + (KN), &Bs[BUF][ldsoff1]);                \
    } while (0)

#define WAITBAR(VM) do {                                            \
        asm volatile("s_waitcnt vmcnt(" VM ")" ::: "memory");       \
        __builtin_amdgcn_s_barrier();                               \
        __builtin_amdgcn_sched_barrier(0);                          \
    } while (0)

#define DOMFMA(RB) do {                                             \
        const bf16_t* Ab = &As[RB][0];                              \
        const bf16_t* Bb = &Bs[RB][0];                              \
        bf16x8 av[4], bv[4];                                        \
        _Pragma("unroll")                                           \
        for (int aa = 0; aa < 4; ++aa) av[aa] = *(const bf16x8*)(Ab + aoff[aa]); \
        _Pragma("unroll")                                           \
        for (int bb = 0; bb < 4; ++bb) bv[bb] = *(const bf16x8*)(Bb + boff[bb]); \
        __builtin_amdgcn_s_setprio(1);                              \
        _Pragma("unroll")                                           \
        for (int aa = 0; aa < 4; ++aa)                              \
            _Pragma("unroll")                                       \
            for (int bb = 0; bb < 4; ++bb)                          \
                accf[aa][bb] = __builtin_amdgcn_mfma_f32_16x16x32_bf16( \
                    av[aa], bv[bb], accf[aa][bb], 0, 0, 0);         \
        __builtin_amdgcn_s_setprio(0);                              \
    } while (0)

    const bf16_t *cA0, *cB0, *cA1, *cB1;
    SETPTRS(tis[0], tjs[0], cA0, cB0, cA1, cB1);
    STAGEP(cA0, cB0, cA1, cB1, 0, 0);        // tile0 stage0 -> buf0
    STAGEP(cA0, cB0, cA1, cB1, BK, 1);       // tile0 stage1 -> buf1

    #pragma unroll
    for (int g = 0; g < 3; ++g) {
        if (g >= ntile) break;
        int has_next = (g + 1 < ntile);
        const bf16_t *nA0 = cA0, *nB0 = cB0, *nA1 = cA1, *nB1 = cB1;
        if (has_next) SETPTRS(tis[g + 1], tjs[g + 1], nA0, nB0, nA1, nB1);

        f32x4 accf[4][4];
        #pragma unroll
        for (int a = 0; a < 4; ++a)
            #pragma unroll
            for (int bb = 0; bb < 4; ++bb)
                accf[a][bb] = (f32x4){0.f, 0.f, 0.f, 0.f};

        // steps 0..13: read buf (g+s)%3, stage s+2 into buf (g+s+2)%3
        int rb = g % 3;
        const bf16_t *pA0 = cA0 + 2 * BK, *pB0 = cB0 + 2 * BK;
        const bf16_t *pA1 = cA1 + 2 * BK, *pB1 = cB1 + 2 * BK;
        for (int s = 0; s < 14; ++s) {
            WAITBAR("4");
            int wb = rb + 2; if (wb >= 3) wb -= 3;
            STAGEP(pA0, pB0, pA1, pB1, 0, wb);
            pA0 += BK; pB0 += BK; pA1 += BK; pB1 += BK;
            DOMFMA(rb);
            ++rb; if (rb == 3) rb = 0;
        }
        // step 14: read buf (g+2)%3; stage NEXT tile's stage0 -> buf (g+1)%3
        WAITBAR("4");
        if (has_next) STAGEP(nA0, nB0, nA1, nB1, 0, (g + 1) % 3);
        DOMFMA((g + 2) % 3);
        // step 15: read buf g%3; stage NEXT tile's stage1 -> buf (g+2)%3
        if (has_next) {
            WAITBAR("4");
            STAGEP(nA0, nB0, nA1, nB1, BK, (g + 2) % 3);
        } else {
            WAITBAR("0");
        }
        DOMFMA(g % 3);

        // epilogue: D2 -> 5-bandwidth RBF (squaring chain: 1 exp + 4 muls)
        int i0 = tis[g] * BT + wr * 64;
        int j0 = tjs[g] * BT + wc * 64;
        float sqi[4][4], sqj[4];
        #pragma unroll
        for (int aa = 0; aa < 4; ++aa)
            #pragma unroll
            for (int r = 0; r < 4; ++r)
                sqi[aa][r] = sqrow[i0 + 16 * aa + q16 * 4 + r];
        #pragma unroll
        for (int bb = 0; bb < 4; ++bb)
            sqj[bb] = sqrow[j0 + 16 * bb + n16];

        float s_local = 0.f;
        #pragma unroll
        for (int aa = 0; aa < 4; ++aa) {
            #pragma unroll
            for (int bb = 0; bb < 4; ++bb) {
                #pragma unroll
                for (int r = 0; r < 4; ++r) {
                    float d2 = fmaf(-2.f, accf[aa][bb][r], sqi[aa][r] + sqj[bb]);
                    d2 = fmaxf(d2, 0.f);
                    float e4 = EXP2F(d2 * c4);
                    float e3 = e4 * e4;
                    float e2 = e3 * e3;
                    float e1 = e2 * e2;
                    float e0 = e1 * e1;
                    s_local += e4 + e3 + e2 + e1 + e0;
                }
            }
        }
        #pragma unroll
        for (int off = 32; off > 0; off >>= 1) s_local += __shfl_down(s_local, off);
        if (lane == 0) wsum[wv] = s_local;
        __syncthreads();   // implicit vmcnt(0): prefetched stages are done by now
        if (t == 0) {
            float bs = wsum[0] + wsum[1] + wsum[2] + wsum[3];
            double si = (tis[g] < NT / 2) ? 1.0 : -1.0;
            double sj = (tjs[g] < NT / 2) ? 1.0 : -1.0;
            double w = si * sj * ((tis[g] == tjs[g]) ? 1.0 : 2.0);
            double oldv = atomicAdd(&acc[(b & 7) * 16], w * (double)bs);
            asm volatile("" :: "v"(oldv));      // keep return live (ordering)
        }
        if (has_next) { cA0 = nA0; cB0 = nB0; cA1 = nA1; cB1 = nB1; }
    }

    // one fence-free ticket per block: all older VMEM (incl. returning
    // atomics) retired by vmcnt(0) before the ticket is taken.
    if (t == 0) {
        asm volatile("s_waitcnt vmcnt(0)" ::: "memory");
        unsigned old = atomicAdd(tk2, 1u);
        if (old == NPERS - 1) {              // last block: final reduce -> out
            double ssum = 0.0;
            #pragma unroll
            for (int i = 0; i < 8; ++i) ssum += atomicAdd(&acc[i * 16], 0.0);
            out[0] = (float)(ssum / ((double)NX * (double)NX));
        }
    }
#undef SETPTRS
#undef STAGEP
#undef WAITBAR
#undef DOMFMA
}

extern "C" void kernel_launch(void* const* d_in, const int* in_sizes, int n_in,
                              void* d_out, int out_size, void* d_ws, size_t ws_size,
                              hipStream_t stream) {
    const float* X = (const float*)d_in[0];
    const float* Y = (const float*)d_in[1];
    float* out = (float*)d_out;

    float*    sqrow  = (float*)d_ws;
    float*    colsum = sqrow + 8192;
    float*    cvals  = (float*)((char*)d_ws + 34816);
    unsigned* tk1    = (unsigned*)((char*)d_ws + 34840);
    unsigned* tk2    = (unsigned*)((char*)d_ws + 34844);
    double*   S1acc  = (double*)((char*)d_ws + 34848);
    double*   acc    = (double*)((char*)d_ws + 34944);
    bf16_t*   Zh     = (bf16_t*)((char*)d_ws + 36864);

    k_prep  <<<2048, 256, 0, stream>>>(X, Y, Zh, sqrow, colsum, tk1, S1acc);
    k_colsum<<<128, 512, 0, stream>>>(Zh, sqrow, colsum, cvals, S1acc, tk1, acc, tk2);
    k_pair  <<<NPERS, 256, 0, stream>>>(Zh, sqrow, cvals, acc, tk2, out);
}